// Round 3
// baseline (595.676 us; speedup 1.0000x reference)
//
#include <hip/hip_runtime.h>
#include <hip/hip_bf16.h>

// GAT layer, N=8192, D_IN=512, D_OUT=128.
// Identity: softmax row-max cancels a1[i]; attention = adj*e^{a2[j]} / sum_j adj*e^{a2[j]}.
// Pipeline (ws = 2.6 MB only):
//   k_cvtW: W[512][128] fp32 -> WT[2][128][512] bf16 hi/lo planes (transposed)
//   k_h   : h = x @ W_fc via bf16 MFMA with hi/lo split (fp32-accurate);
//           a2 = h.w_a2 in-block; writes G^T[144][8192] bf16 directly
//           (rows 0..127 = e_j*h_jd, row 128 = e_j, 129..143 = 0). h never stored.
//   k_gat : out = (adj @ G) / den. 256 blocks x 1024 thr (16 waves = 4/SIMD).
//           BM=32, in-block split-K x2, waves = 2ks x 2wm x 4wc.
//           A: per-wave depth-2 reg prefetch + cheap {0,1}->bf16 pack.
//           B: global bf16x8 from L2 (604 MB total). LDS merge + den-divide epilogue.

#define NN 8192
#define DIN 512
#define DOUT 128

typedef __attribute__((ext_vector_type(4))) int   int4v;
typedef __attribute__((ext_vector_type(4))) float f32x4;
typedef __attribute__((ext_vector_type(8))) short bf16x8;

static __device__ __forceinline__ unsigned short f2bf(float f) {
    unsigned u = __float_as_uint(f);
    unsigned r = (u + 0x7FFFu + ((u >> 16) & 1u)) >> 16;
    return (unsigned short)r;
}
static __device__ __forceinline__ float bf2f(unsigned short b) {
    return __uint_as_float((unsigned)b << 16);
}

// ---------------- k_cvtW: W -> WT[2][128][512] bf16 (hi, lo residual) ----------------
__global__ __launch_bounds__(256) void k_cvtW(const float* __restrict__ W,
                                              unsigned short* __restrict__ WT) {
    __shared__ float s[8][128];
    const int t  = threadIdx.x;
    const int k0 = blockIdx.x * 8;      // grid 64
    {
        int idx = t * 4;
        int k = idx >> 7, d = idx & 127;
        float4 v = *reinterpret_cast<const float4*>(&W[(size_t)(k0 + k) * DOUT + d]);
        *reinterpret_cast<float4*>(&s[k][d]) = v;
    }
    __syncthreads();
    const int d  = t & 127;
    const int pl = t >> 7;              // 0 = hi, 1 = lo
    unsigned short o[8];
    #pragma unroll
    for (int kk = 0; kk < 8; ++kk) {
        float f = s[kk][d];
        unsigned short hb = f2bf(f);
        o[kk] = pl ? f2bf(f - bf2f(hb)) : hb;
    }
    *reinterpret_cast<uint4*>(&WT[(size_t)pl * 128 * DIN + (size_t)d * DIN + k0]) =
        *reinterpret_cast<const uint4*>(o);
}

// ---------------- k_h: h-GEMM (hi/lo bf16) + a2 + G^T build, h stays on-chip ----------------
__global__ __launch_bounds__(256) void k_h(const float* __restrict__ x,
                                           const unsigned short* __restrict__ WT,
                                           const float* __restrict__ wa2,
                                           unsigned short* __restrict__ Gt) {
    __shared__ float red[4][16];
    __shared__ float es[16];
    const int t = threadIdx.x;
    const int w = t >> 6, l = t & 63;
    const int c = l & 15, g = l >> 4;
    const int j0 = blockIdx.x * 16;     // grid 512

    f32x4 acc[2]; acc[0] = (f32x4)0.f; acc[1] = (f32x4)0.f;

    const float* xrow = x + (size_t)(j0 + c) * DIN + g * 8;
    const unsigned short* b0h = WT + (size_t)((w * 2 + 0) * 16 + c) * DIN + g * 8;
    const unsigned short* b1h = WT + (size_t)((w * 2 + 1) * 16 + c) * DIN + g * 8;
    const unsigned short* b0l = b0h + 128 * DIN;
    const unsigned short* b1l = b1h + 128 * DIN;

    for (int kt = 0; kt < DIN; kt += 32) {
        float4 v0 = *reinterpret_cast<const float4*>(xrow + kt);
        float4 v1 = *reinterpret_cast<const float4*>(xrow + kt + 4);
        float vf[8] = {v0.x, v0.y, v0.z, v0.w, v1.x, v1.y, v1.z, v1.w};
        bf16x8 ahi, alo;
        #pragma unroll
        for (int e = 0; e < 8; ++e) {
            unsigned short hb = f2bf(vf[e]);
            ahi[e] = (short)hb;
            alo[e] = (short)f2bf(vf[e] - bf2f(hb));
        }
        bf16x8 bh0 = *reinterpret_cast<const bf16x8*>(b0h + kt);
        bf16x8 bh1 = *reinterpret_cast<const bf16x8*>(b1h + kt);
        bf16x8 bl0 = *reinterpret_cast<const bf16x8*>(b0l + kt);
        bf16x8 bl1 = *reinterpret_cast<const bf16x8*>(b1l + kt);
        acc[0] = __builtin_amdgcn_mfma_f32_16x16x32_bf16(ahi, bh0, acc[0], 0, 0, 0);
        acc[1] = __builtin_amdgcn_mfma_f32_16x16x32_bf16(ahi, bh1, acc[1], 0, 0, 0);
        acc[0] = __builtin_amdgcn_mfma_f32_16x16x32_bf16(ahi, bl0, acc[0], 0, 0, 0);
        acc[1] = __builtin_amdgcn_mfma_f32_16x16x32_bf16(ahi, bl1, acc[1], 0, 0, 0);
        acc[0] = __builtin_amdgcn_mfma_f32_16x16x32_bf16(alo, bh0, acc[0], 0, 0, 0);
        acc[1] = __builtin_amdgcn_mfma_f32_16x16x32_bf16(alo, bh1, acc[1], 0, 0, 0);
    }

    // a2 partial: this wave covers cols (w*2..w*2+1)*16 + c
    const float wl0 = wa2[(w * 2 + 0) * 16 + c];
    const float wl1 = wa2[(w * 2 + 1) * 16 + c];
    #pragma unroll
    for (int r = 0; r < 4; ++r) {
        float p = acc[0][r] * wl0 + acc[1][r] * wl1;
        p += __shfl_xor(p, 1); p += __shfl_xor(p, 2);
        p += __shfl_xor(p, 4); p += __shfl_xor(p, 8);
        if (c == 0) red[w][g * 4 + r] = p;
    }
    __syncthreads();
    if (t < 16) es[t] = expf(red[0][t] + red[1][t] + red[2][t] + red[3][t]);
    __syncthreads();

    #pragma unroll
    for (int ci = 0; ci < 2; ++ci) {
        unsigned short b[4];
        #pragma unroll
        for (int r = 0; r < 4; ++r) b[r] = f2bf(acc[ci][r] * es[g * 4 + r]);
        unsigned u0 = (unsigned)b[0] | ((unsigned)b[1] << 16);
        unsigned u1 = (unsigned)b[2] | ((unsigned)b[3] << 16);
        uint2 uv = {u0, u1};
        *reinterpret_cast<uint2*>(&Gt[(size_t)((w * 2 + ci) * 16 + c) * NN + j0 + g * 4]) = uv;
    }
    // row 128 = e_j; rows 129..143 = 0
    if (t < 8) {
        unsigned u = (unsigned)f2bf(es[t * 2]) | ((unsigned)f2bf(es[t * 2 + 1]) << 16);
        reinterpret_cast<unsigned*>(&Gt[(size_t)128 * NN + j0])[t] = u;
    }
    if (t >= 16 && t < 76) {
        int zr = 129 + ((t - 16) >> 2), zc = (t - 16) & 3;
        uint2 z = {0u, 0u};
        *reinterpret_cast<uint2*>(&Gt[(size_t)zr * NN + j0 + zc * 4]) = z;
    }
}

// ---------------- k_gat: out = (adj @ G) / den ----------------
static __device__ __forceinline__ int4v ld4(const int* p) {
    return *reinterpret_cast<const int4v*>(p);
}
// {0,1} int pairs -> packed bf16 {0,1.0}: (lo | hi<<16) * 0x3F80 (carry-free)
static __device__ __forceinline__ bf16x8 adj2bf(int4v a, int4v b) {
    unsigned u0 = ((unsigned)a.x | ((unsigned)a.y << 16)) * 0x3F80u;
    unsigned u1 = ((unsigned)a.z | ((unsigned)a.w << 16)) * 0x3F80u;
    unsigned u2 = ((unsigned)b.x | ((unsigned)b.y << 16)) * 0x3F80u;
    unsigned u3 = ((unsigned)b.z | ((unsigned)b.w << 16)) * 0x3F80u;
    int4v p = {(int)u0, (int)u1, (int)u2, (int)u3};
    return __builtin_bit_cast(bf16x8, p);
}

__global__ __launch_bounds__(1024, 4) void k_gat(const int* __restrict__ adj,
                                                 const unsigned short* __restrict__ Gt,
                                                 float* __restrict__ out) {
    __shared__ float red[8][64][13];   // ks=1 partials (pad 13: conflict-light)
    __shared__ float den_l[32];
    const int t  = threadIdx.x;
    const int w  = t >> 6, l = t & 63;
    const int ks = w >> 3;             // K half
    const int wm = (w >> 2) & 1;       // m-tile
    const int wc = w & 3;              // col group: {0,1},{2,3},{4,5},{6,7,8}
    const int c  = l & 15, g = l >> 4;
    const int nct = (wc == 3) ? 3 : 2;
    const int ct0 = wc * 2;
    const int row0 = blockIdx.x * 32 + wm * 16;   // grid 256
    const int k0   = ks * 4096;

    f32x4 acc[3];
    acc[0] = (f32x4)0.f; acc[1] = (f32x4)0.f; acc[2] = (f32x4)0.f;

    const int* arow = adj + (size_t)(row0 + c) * NN + k0 + g * 8;
    const unsigned short* bp0 = Gt + (size_t)((ct0 + 0) * 16 + c) * NN + k0 + g * 8;
    const unsigned short* bp1 = Gt + (size_t)((ct0 + 1) * 16 + c) * NN + k0 + g * 8;
    const unsigned short* bp2 = Gt + (size_t)((ct0 + 2) * 16 + c) * NN + k0 + g * 8;

    // depth-2 K-32 register prefetch of A
    int4v a0A = ld4(arow +  0), a0B = ld4(arow +  4);
    int4v a1A = ld4(arow + 32), a1B = ld4(arow + 36);

    for (int it = 0; it < 128; it += 2) {
        {   // K-32 step `it`
            bf16x8 a = adj2bf(a0A, a0B);
            if (it + 2 < 128) {
                const int* p = arow + (it + 2) * 32;
                a0A = ld4(p); a0B = ld4(p + 4);
            }
            bf16x8 b0 = *reinterpret_cast<const bf16x8*>(bp0 + it * 32);
            bf16x8 b1 = *reinterpret_cast<const bf16x8*>(bp1 + it * 32);
            acc[0] = __builtin_amdgcn_mfma_f32_16x16x32_bf16(a, b0, acc[0], 0, 0, 0);
            acc[1] = __builtin_amdgcn_mfma_f32_16x16x32_bf16(a, b1, acc[1], 0, 0, 0);
            if (nct == 3) {
                bf16x8 b2 = *reinterpret_cast<const bf16x8*>(bp2 + it * 32);
                acc[2] = __builtin_amdgcn_mfma_f32_16x16x32_bf16(a, b2, acc[2], 0, 0, 0);
            }
        }
        {   // K-32 step `it+1`
            bf16x8 a = adj2bf(a1A, a1B);
            if (it + 3 < 128) {
                const int* p = arow + (it + 3) * 32;
                a1A = ld4(p); a1B = ld4(p + 4);
            }
            bf16x8 b0 = *reinterpret_cast<const bf16x8*>(bp0 + (it + 1) * 32);
            bf16x8 b1 = *reinterpret_cast<const bf16x8*>(bp1 + (it + 1) * 32);
            acc[0] = __builtin_amdgcn_mfma_f32_16x16x32_bf16(a, b0, acc[0], 0, 0, 0);
            acc[1] = __builtin_amdgcn_mfma_f32_16x16x32_bf16(a, b1, acc[1], 0, 0, 0);
            if (nct == 3) {
                bf16x8 b2 = *reinterpret_cast<const bf16x8*>(bp2 + (it + 1) * 32);
                acc[2] = __builtin_amdgcn_mfma_f32_16x16x32_bf16(a, b2, acc[2], 0, 0, 0);
            }
        }
    }

    // merge K-halves: ks=1 -> LDS, ks=0 adds
    if (ks == 1) {
        #pragma unroll
        for (int ci = 0; ci < 3; ++ci)
            #pragma unroll
            for (int r = 0; r < 4; ++r) red[w - 8][l][ci * 4 + r] = acc[ci][r];
    }
    __syncthreads();
    if (ks == 0) {
        #pragma unroll
        for (int ci = 0; ci < 3; ++ci)
            #pragma unroll
            for (int r = 0; r < 4; ++r) acc[ci][r] += red[w][l][ci * 4 + r];
        if (wc == 3 && c == 0) {   // den = col 128 (ct=8, c=0)
            #pragma unroll
            for (int r = 0; r < 4; ++r) den_l[wm * 16 + g * 4 + r] = acc[2][r];
        }
    }
    __syncthreads();
    if (ks == 0) {
        #pragma unroll
        for (int r = 0; r < 4; ++r) {
            float inv = 1.0f / den_l[wm * 16 + g * 4 + r];
            float* orow = out + (size_t)(row0 + g * 4 + r) * DOUT + ct0 * 16 + c;
            orow[0]  = acc[0][r] * inv;
            orow[16] = acc[1][r] * inv;
            if (wc == 3 && false) {}   // ct=8 is den, not written
        }
    }
}

extern "C" void kernel_launch(void* const* d_in, const int* in_sizes, int n_in,
                              void* d_out, int out_size, void* d_ws, size_t ws_size,
                              hipStream_t stream) {
    const float* x   = (const float*)d_in[0];
    const int*   adj = (const int*)d_in[1];
    const float* W   = (const float*)d_in[2];
    // d_in[3] = w_a1: unused — cancels in row softmax.
    const float* wa2 = (const float*)d_in[4];
    float* out = (float*)d_out;

    char* ws = (char*)d_ws;
    unsigned short* WT = (unsigned short*)ws;                   // 256 KB
    unsigned short* Gt = (unsigned short*)(ws + 262144);        // 2.36 MB

    k_cvtW<<< 64,  256, 0, stream>>>(W, WT);
    k_h   <<<512,  256, 0, stream>>>(x, WT, wa2, Gt);
    k_gat <<<256, 1024, 0, stream>>>(adj, Gt, out);
}

// Round 4
// 400.524 us; speedup vs baseline: 1.4872x; 1.4872x over previous
//
#include <hip/hip_runtime.h>
#include <hip/hip_bf16.h>

// GAT layer, N=8192, D_IN=512, D_OUT=128.
// Identity: softmax row-max cancels a1[i]; attention_ij = adj_ij*e^{a2_j} / sum_j adj_ij*e^{a2_j}.
// Pipeline (ws = 2.4 MB):
//   k_cvtW: W[512][128] fp32 -> WT[2][128][512] bf16 hi/lo planes (transposed)
//   k_h   : h = x @ W via 3-term hi/lo bf16 MFMA (fp32-accurate); a2+exp fused;
//           writes Gt[129][8192] bf16: rows 0..127 = e_j*h_jd, row 128 = e_j.
//   k_gat : out = (adj @ G) / den. Double-buffered LDS GEMM, BM=32 BK=128,
//           grid 256 x 512thr. adj reg-staged+converted to swizzled LDS (T14);
//           Gt staged via global_load_lds w=16 (linear dest, pre-swizzled src);
//           den accumulated in VALU from adj regs during convert. 1 barrier/iter.

#define NN 8192
#define DIN 512
#define DOUT 128

typedef __attribute__((ext_vector_type(4))) int   int4v;
typedef __attribute__((ext_vector_type(4))) float f32x4;
typedef __attribute__((ext_vector_type(8))) short bf16x8;

static __device__ __forceinline__ unsigned short f2bf(float f) {
    unsigned u = __float_as_uint(f);
    return (unsigned short)((u + 0x7FFFu + ((u >> 16) & 1u)) >> 16);
}
static __device__ __forceinline__ float bf2f(unsigned short b) {
    return __uint_as_float((unsigned)b << 16);
}
static __device__ __forceinline__ void gload_lds16(const void* g, void* l) {
    __builtin_amdgcn_global_load_lds(
        (const __attribute__((address_space(1))) unsigned*)g,
        (__attribute__((address_space(3))) unsigned*)l, 16, 0, 0);
}
static __device__ __forceinline__ int4v ntld(const int* p) {
    return __builtin_nontemporal_load(reinterpret_cast<const int4v*>(p));
}

// ---------------- k_cvtW: W -> WT[2][128][512] bf16 (hi, lo residual) ----------------
__global__ __launch_bounds__(256) void k_cvtW(const float* __restrict__ W,
                                              unsigned short* __restrict__ WT) {
    __shared__ float s[8][128];
    const int t  = threadIdx.x;
    const int k0 = blockIdx.x * 8;      // grid 64
    {
        int idx = t * 4;
        int k = idx >> 7, d = idx & 127;
        float4 v = *reinterpret_cast<const float4*>(&W[(size_t)(k0 + k) * DOUT + d]);
        *reinterpret_cast<float4*>(&s[k][d]) = v;
    }
    __syncthreads();
    const int d  = t & 127;
    const int pl = t >> 7;              // 0 = hi, 1 = lo
    unsigned short o[8];
    #pragma unroll
    for (int kk = 0; kk < 8; ++kk) {
        float f = s[kk][d];
        unsigned short hb = f2bf(f);
        o[kk] = pl ? f2bf(f - bf2f(hb)) : hb;
    }
    *reinterpret_cast<uint4*>(&WT[(size_t)pl * 128 * DIN + (size_t)d * DIN + k0]) =
        *reinterpret_cast<const uint4*>(o);
}

// ---------------- k_h: h-GEMM + a2 + Gt build ----------------
// grid 512, 512 thr (8 waves). Wave w owns output cols w*16..w*16+15 for 16 rows.
__global__ __launch_bounds__(512, 2) void k_h(const float* __restrict__ x,
                                              const unsigned short* __restrict__ WT,
                                              const float* __restrict__ wa2,
                                              unsigned short* __restrict__ Gt) {
    __shared__ __align__(16) char xls[16384];   // [buf][plane][16 rows][128 bf16] swizzled
    __shared__ float red[8][16];
    __shared__ float es[16];
    const int t = threadIdx.x;
    const int w = t >> 6, l = t & 63;
    const int c = l & 15, g = l >> 4;
    const int j0 = blockIdx.x * 16;

    f32x4 acc = (f32x4)0.f;

    // staging: 1 float4/thread per tile
    const int srow = t >> 5;            // 0..15
    const int sc4  = t & 31;            // float4 within row
    const unsigned wbyte = (unsigned)srow * 256 +
                           (((unsigned)(sc4 * 8)) ^ (((unsigned)(srow & 15)) << 4));
    const float* xp = x + (size_t)(j0 + srow) * DIN + sc4 * 4;

    const unsigned short* bhp = WT + (size_t)(w * 16 + c) * DIN + g * 8;
    const unsigned short* blp = bhp + 128 * DIN;
    const unsigned rswz = ((unsigned)c) << 4;

    float4 xv = *reinterpret_cast<const float4*>(xp);   // tile 0

    for (int kt = 0; kt < 4; ++kt) {
        const int cur = kt & 1;
        char* ph = xls + (cur * 2 + 0) * 4096;
        char* pl_ = xls + (cur * 2 + 1) * 4096;
        {   // convert + write tile kt
            float vf[4] = {xv.x, xv.y, xv.z, xv.w};
            unsigned short hb[4], lb[4];
            #pragma unroll
            for (int e2 = 0; e2 < 4; ++e2) {
                hb[e2] = f2bf(vf[e2]);
                lb[e2] = f2bf(vf[e2] - bf2f(hb[e2]));
            }
            uint2 hv = {(unsigned)hb[0] | ((unsigned)hb[1] << 16),
                        (unsigned)hb[2] | ((unsigned)hb[3] << 16)};
            uint2 lv = {(unsigned)lb[0] | ((unsigned)lb[1] << 16),
                        (unsigned)lb[2] | ((unsigned)lb[3] << 16)};
            *reinterpret_cast<uint2*>(ph  + wbyte) = hv;
            *reinterpret_cast<uint2*>(pl_ + wbyte) = lv;
        }
        if (kt < 3) xv = *reinterpret_cast<const float4*>(xp + (kt + 1) * 128);
        __syncthreads();
        #pragma unroll
        for (int ks = 0; ks < 4; ++ks) {
            unsigned ro = ((unsigned)(ks * 64 + g * 16)) ^ rswz;
            bf16x8 ah = *reinterpret_cast<const bf16x8*>(ph  + c * 256 + ro);
            bf16x8 al = *reinterpret_cast<const bf16x8*>(pl_ + c * 256 + ro);
            bf16x8 bh = *reinterpret_cast<const bf16x8*>(bhp + kt * 128 + ks * 32);
            bf16x8 bl = *reinterpret_cast<const bf16x8*>(blp + kt * 128 + ks * 32);
            acc = __builtin_amdgcn_mfma_f32_16x16x32_bf16(ah, bh, acc, 0, 0, 0);
            acc = __builtin_amdgcn_mfma_f32_16x16x32_bf16(ah, bl, acc, 0, 0, 0);
            acc = __builtin_amdgcn_mfma_f32_16x16x32_bf16(al, bh, acc, 0, 0, 0);
        }
        __syncthreads();
    }

    // a2 reduce + exp
    const float wl = wa2[w * 16 + c];
    #pragma unroll
    for (int r = 0; r < 4; ++r) {
        float p = acc[r] * wl;
        p += __shfl_xor(p, 1); p += __shfl_xor(p, 2);
        p += __shfl_xor(p, 4); p += __shfl_xor(p, 8);
        if (c == 0) red[w][g * 4 + r] = p;
    }
    __syncthreads();
    if (t < 16) {
        float s = 0.f;
        #pragma unroll
        for (int ww = 0; ww < 8; ++ww) s += red[ww][t];
        es[t] = expf(s);
    }
    __syncthreads();
    {   // Gt rows 0..127: col d = w*16+c, rows j0+g*4..+3
        unsigned short b[4];
        #pragma unroll
        for (int r = 0; r < 4; ++r) b[r] = f2bf(acc[r] * es[g * 4 + r]);
        uint2 uv = {(unsigned)b[0] | ((unsigned)b[1] << 16),
                    (unsigned)b[2] | ((unsigned)b[3] << 16)};
        *reinterpret_cast<uint2*>(&Gt[(size_t)(w * 16 + c) * NN + j0 + g * 4]) = uv;
    }
    if (t < 8) {   // row 128 = e_j
        unsigned u = (unsigned)f2bf(es[t * 2]) | ((unsigned)f2bf(es[t * 2 + 1]) << 16);
        reinterpret_cast<unsigned*>(&Gt[(size_t)128 * NN + j0])[t] = u;
    }
}

// ---------------- k_gat: out = (adj @ G) / den ----------------
// grid 256, 512 thr = 8 waves (2 wm x 4 wc). BM=32, BK=128, dbuf LDS, 1 barrier/iter.
__global__ __launch_bounds__(512, 2) void k_gat(const int* __restrict__ adj,
                                                const unsigned short* __restrict__ Gt,
                                                float* __restrict__ out) {
    // LDS map: A bufs @0,@8192 (32x128 bf16 swz); B bufs @16384,@49152 (128x128 bf16 swz);
    //          denp @81920 (f32[32][32]); den_l @86016 (f32[32])
    __shared__ __align__(16) char lds[86144];
    const int t = threadIdx.x;
    const int w = t >> 6, l = t & 63;
    const int c = l & 15, g = l >> 4;
    const int wm = w >> 2, wc = w & 3;
    const int row0 = blockIdx.x * 32;

    float* denp  = (float*)(lds + 81920);
    float* den_l = (float*)(lds + 86016);

    f32x4 acc0 = (f32x4)0.f, acc1 = (f32x4)0.f;

    // A staging: thread handles int4 granules i0=t (rows 0..15), i1=t+512 (rows 16..31)
    const int r0 = t >> 5;              // 0..15
    const int kg = t & 31;              // int4 granule within row
    const int* ap0 = adj + (size_t)(row0 + r0) * NN + kg * 4;
    const int* ap1 = adj + (size_t)(row0 + 16 + r0) * NN + kg * 4;
    const unsigned short* ep = Gt + (size_t)128 * NN + kg * 4;
    const unsigned aswz = ((unsigned)(r0 & 15)) << 4;
    const unsigned aw0  = (unsigned)r0 * 256 + (((unsigned)(kg * 8)) ^ aswz);
    const unsigned aw1  = aw0 + 16 * 256;

    float d0 = 0.f, d1 = 0.f;

    // frag-read constants
    const unsigned arow = (unsigned)(wm * 16 + c);
    const unsigned abase = arow * 256;
    const unsigned afswz = ((unsigned)c) << 4;
    const unsigned br0 = (unsigned)(wc * 32 + c);
    const unsigned br1 = br0 + 16;

    // ---- prologue: stage tile 0 ----
    int4v a0 = ntld(ap0), a1 = ntld(ap1);
    uint2 ev = *reinterpret_cast<const uint2*>(ep);
    #pragma unroll
    for (int s = 0; s < 4; ++s) {
        int ii = t + s * 512;
        int rb = ii >> 4, pb = ii & 15;
        int gk = pb ^ (rb & 15);
        gload_lds16(Gt + (size_t)rb * NN + gk * 8, lds + 16384 + ii * 16);
    }
    {   // convert + ds_write A tile 0, den accum
        unsigned u00 = ((unsigned)a0.x | ((unsigned)a0.y << 16)) * 0x3F80u;
        unsigned u01 = ((unsigned)a0.z | ((unsigned)a0.w << 16)) * 0x3F80u;
        unsigned u10 = ((unsigned)a1.x | ((unsigned)a1.y << 16)) * 0x3F80u;
        unsigned u11 = ((unsigned)a1.z | ((unsigned)a1.w << 16)) * 0x3F80u;
        uint2 w0 = {u00, u01}, w1 = {u10, u11};
        *reinterpret_cast<uint2*>(lds + aw0) = w0;
        *reinterpret_cast<uint2*>(lds + aw1) = w1;
        float e0 = bf2f((unsigned short)(ev.x & 0xFFFF)), e1 = bf2f((unsigned short)(ev.x >> 16));
        float e2 = bf2f((unsigned short)(ev.y & 0xFFFF)), e3 = bf2f((unsigned short)(ev.y >> 16));
        d0 += (a0.x ? e0 : 0.f) + (a0.y ? e1 : 0.f) + (a0.z ? e2 : 0.f) + (a0.w ? e3 : 0.f);
        d1 += (a1.x ? e0 : 0.f) + (a1.y ? e1 : 0.f) + (a1.z ? e2 : 0.f) + (a1.w ? e3 : 0.f);
    }
    __syncthreads();

    int cur = 0;
    for (int kt = 0; kt < 64; ++kt) {
        const int nb = cur ^ 1;
        if (kt < 63) {   // issue next-tile stage loads FIRST (MLP across whole tile)
            const int ko = (kt + 1) * 128;
            a0 = ntld(ap0 + ko);
            a1 = ntld(ap1 + ko);
            ev = *reinterpret_cast<const uint2*>(ep + ko);
            char* Bn = lds + 16384 + nb * 32768;
            #pragma unroll
            for (int s = 0; s < 4; ++s) {
                int ii = t + s * 512;
                int rb = ii >> 4, pb = ii & 15;
                int gk = pb ^ (rb & 15);
                gload_lds16(Gt + (size_t)rb * NN + ko + gk * 8, Bn + ii * 16);
            }
        }
        // compute tile kt from buf cur
        const char* Ab = lds + cur * 8192;
        const char* Bb = lds + 16384 + cur * 32768;
        #pragma unroll
        for (int ks = 0; ks < 4; ++ks) {
            unsigned ko16 = (unsigned)(ks * 64 + g * 16);
            bf16x8 av = *reinterpret_cast<const bf16x8*>(Ab + abase + (ko16 ^ afswz));
            bf16x8 b0 = *reinterpret_cast<const bf16x8*>(Bb + br0 * 256 + (ko16 ^ (((br0 & 15)) << 4)));
            bf16x8 b1 = *reinterpret_cast<const bf16x8*>(Bb + br1 * 256 + (ko16 ^ (((br1 & 15)) << 4)));
            acc0 = __builtin_amdgcn_mfma_f32_16x16x32_bf16(av, b0, acc0, 0, 0, 0);
            acc1 = __builtin_amdgcn_mfma_f32_16x16x32_bf16(av, b1, acc1, 0, 0, 0);
        }
        if (kt < 63) {   // convert + write A tile kt+1, den accum
            char* An = lds + nb * 8192;
            unsigned u00 = ((unsigned)a0.x | ((unsigned)a0.y << 16)) * 0x3F80u;
            unsigned u01 = ((unsigned)a0.z | ((unsigned)a0.w << 16)) * 0x3F80u;
            unsigned u10 = ((unsigned)a1.x | ((unsigned)a1.y << 16)) * 0x3F80u;
            unsigned u11 = ((unsigned)a1.z | ((unsigned)a1.w << 16)) * 0x3F80u;
            uint2 w0 = {u00, u01}, w1 = {u10, u11};
            *reinterpret_cast<uint2*>(An + aw0) = w0;
            *reinterpret_cast<uint2*>(An + aw1) = w1;
            float e0 = bf2f((unsigned short)(ev.x & 0xFFFF)), e1 = bf2f((unsigned short)(ev.x >> 16));
            float e2 = bf2f((unsigned short)(ev.y & 0xFFFF)), e3 = bf2f((unsigned short)(ev.y >> 16));
            d0 += (a0.x ? e0 : 0.f) + (a0.y ? e1 : 0.f) + (a0.z ? e2 : 0.f) + (a0.w ? e3 : 0.f);
            d1 += (a1.x ? e0 : 0.f) + (a1.y ? e1 : 0.f) + (a1.z ? e2 : 0.f) + (a1.w ? e3 : 0.f);
        }
        __syncthreads();
        cur ^= 1;
    }

    // den reduce: 32 partials per row
    denp[r0 * 32 + kg] = d0;
    denp[(16 + r0) * 32 + kg] = d1;
    __syncthreads();
    if (t < 32) {
        float s = 0.f;
        #pragma unroll
        for (int q = 0; q < 32; ++q) s += denp[t * 32 + q];
        den_l[t] = s;
    }
    __syncthreads();

    #pragma unroll
    for (int r = 0; r < 4; ++r) {
        float inv = 1.0f / den_l[wm * 16 + g * 4 + r];
        float* orow = out + (size_t)(row0 + wm * 16 + g * 4 + r) * DOUT + wc * 32 + c;
        orow[0]  = acc0[r] * inv;
        orow[16] = acc1[r] * inv;
    }
}

extern "C" void kernel_launch(void* const* d_in, const int* in_sizes, int n_in,
                              void* d_out, int out_size, void* d_ws, size_t ws_size,
                              hipStream_t stream) {
    const float* x   = (const float*)d_in[0];
    const int*   adj = (const int*)d_in[1];
    const float* W   = (const float*)d_in[2];
    // d_in[3] = w_a1: unused — cancels in row softmax.
    const float* wa2 = (const float*)d_in[4];
    float* out = (float*)d_out;

    char* ws = (char*)d_ws;
    unsigned short* WT = (unsigned short*)ws;                   // 256 KB
    unsigned short* Gt = (unsigned short*)(ws + 262144);        // 129*8192*2 = 2.064 MB

    k_cvtW<<< 64, 256, 0, stream>>>(W, WT);
    k_h   <<<512, 512, 0, stream>>>(x, WT, wa2, Gt);
    k_gat <<<256, 512, 0, stream>>>(adj, Gt, out);
}